// Round 5
// baseline (462.326 us; speedup 1.0000x reference)
//
#include <hip/hip_runtime.h>
#include <stdint.h>

typedef __attribute__((ext_vector_type(4))) int int4v;
typedef __attribute__((ext_vector_type(16))) int int16v;
typedef __attribute__((ext_vector_type(4))) uint32_t uint4v;

#define M_DIM 8192
#define N_DIM 4096
#define K_DIM 4096

// K-permuted layout: within each 64-byte K chunk, stored byte p holds
// original k = (p>>2) + 16*(p&3). Applied identically to A and B => MFMA
// dot products unchanged. GEMM XOR-swizzles 16-B chunks within each 128-B
// LDS row (slot = chunk ^ (row&7)), applied at the global source address
// during staging and inverted at fragment-read.

// ---------------- pack x: int32 -> int8, K-permuted ----------------
__global__ void pack_a_perm(const int* __restrict__ x, uint4v* __restrict__ a8) {
    const int g = blockIdx.x * blockDim.x + threadIdx.x;
    const int w0 = (g & 3) * 4;
    const int chunk = g >> 2;
    const int* base = x + (size_t)chunk * 64;
    int4v L[4];
#pragma unroll
    for (int j = 0; j < 4; ++j) L[j] = *(const int4v*)(base + j * 16 + w0);
    uint4v outv;
#pragma unroll
    for (int wi = 0; wi < 4; ++wi) {
        outv[wi] = (uint32_t)(L[0][wi] & 0xff) | ((uint32_t)(L[1][wi] & 0xff) << 8) |
                   ((uint32_t)(L[2][wi] & 0xff) << 16) | ((uint32_t)(L[3][wi] & 0xff) << 24);
    }
    a8[g] = outv;
}

// ------- transpose+pack weight: [K][N] int32 -> Bt[N][K-permuted] int8 -------
__global__ void transpose_b_perm(const int* __restrict__ w, int8_t* __restrict__ bt) {
    const int t = threadIdx.x;
    const int kt = blockIdx.y * 64;
    const int n0 = blockIdx.x * 64;
    const int c4 = t & 3;
    const int n = t >> 2;
    const int w0 = c4 * 4;
    const int* col = w + (size_t)kt * N_DIM + n0 + n;
    uint4v outv;
#pragma unroll
    for (int wi = 0; wi < 4; ++wi) {
        uint32_t p = 0;
#pragma unroll
        for (int j = 0; j < 4; ++j) {
            uint32_t b = (uint32_t)(col[(size_t)(w0 + wi + 16 * j) * N_DIM] & 0xff);
            p |= b << (8 * j);
        }
        outv[wi] = p;
    }
    *(uint4v*)&bt[(size_t)(n0 + n) * K_DIM + kt + w0 * 4] = outv;
}

// -------- GEMM: block 256x128, wave 128x64 (4x2 of 32x32x32), BK=128 --------
__device__ inline void async16(const void* g, void* l) {
    __builtin_amdgcn_global_load_lds(
        (const __attribute__((address_space(1))) uint32_t*)g,
        (__attribute__((address_space(3))) uint32_t*)l, 16, 0, 0);
}

__global__ void __launch_bounds__(256)
gemm_kernel(const int8_t* __restrict__ A, const int8_t* __restrict__ Bt,
            const float* __restrict__ pa, const float* __restrict__ pb,
            int* __restrict__ out) {
    __shared__ int8_t smem[49152];
    int8_t* As = smem;            // [256 rows][128 B], chunk-swizzled
    int8_t* Bs = smem + 32768;    // [128 rows][128 B]

    const int t = threadIdx.x;
    const int lane = t & 63;
    const int wave = t >> 6;
    const int m0 = blockIdx.y * 256;
    const int n0 = blockIdx.x * 128;
    const int wm = (wave >> 1) * 128;   // wave M offset (2 waves in M)
    const int wn = (wave & 1) * 64;     // wave N offset (2 waves in N)
    const float scale = pa[0] * pb[0];

    int16v acc[4][2];
#pragma unroll
    for (int i = 0; i < 4; ++i)
#pragma unroll
        for (int j = 0; j < 2; ++j)
#pragma unroll
            for (int r = 0; r < 16; ++r) acc[i][j][r] = 0;

    const int srow = lane >> 3;   // staging row within 8-row group
    const int sslot = lane & 7;   // 16-B slot within 128-B row
    const int l31 = lane & 31;
    const int fg = lane >> 5;     // k-half selector

    for (int kt = 0; kt < K_DIM; kt += 128) {
        __syncthreads();
#pragma unroll
        for (int s = 0; s < 8; ++s) {                 // A: 256 rows
            const int base_row = wave * 8 + s * 32;   // wave-uniform
            const int row = base_row + srow;
            const int c = ((sslot ^ (row & 7)) * 16);
            async16(A + (size_t)(m0 + row) * K_DIM + kt + c, As + base_row * 128);
        }
#pragma unroll
        for (int s = 0; s < 4; ++s) {                 // B: 128 rows
            const int base_row = wave * 8 + s * 32;
            const int row = base_row + srow;
            const int c = ((sslot ^ (row & 7)) * 16);
            async16(Bt + (size_t)(n0 + row) * K_DIM + kt + c, Bs + base_row * 128);
        }
        __syncthreads();

#pragma unroll
        for (int ks = 0; ks < 4; ++ks) {
            const int cc = ks * 2 + fg;
            int4v af[4], bf[2];
#pragma unroll
            for (int i = 0; i < 4; ++i) {
                const int ra = wm + i * 32 + l31;
                af[i] = *(const int4v*)&As[ra * 128 + ((cc ^ (ra & 7)) * 16)];
            }
#pragma unroll
            for (int j = 0; j < 2; ++j) {
                const int rb = wn + j * 32 + l31;
                bf[j] = *(const int4v*)&Bs[rb * 128 + ((cc ^ (rb & 7)) * 16)];
            }
#pragma unroll
            for (int i = 0; i < 4; ++i)
#pragma unroll
                for (int j = 0; j < 2; ++j)
                    acc[i][j] = __builtin_amdgcn_mfma_i32_32x32x32_i8(af[i], bf[j],
                                                                       acc[i][j], 0, 0, 0);
        }
    }

    const int col = lane & 31;
    const int rbase = (lane >> 5) * 4;
#pragma unroll
    for (int i = 0; i < 4; ++i)
#pragma unroll
        for (int j = 0; j < 2; ++j)
#pragma unroll
            for (int r = 0; r < 16; ++r) {
                const int rowf = rbase + (r & 3) + 8 * (r >> 2);
                float v = (float)acc[i][j][r] * scale;
                v = rintf(v);
                v = fminf(127.f, fmaxf(-128.f, v));
                out[(size_t)(m0 + wm + i * 32 + rowf) * N_DIM +
                    (n0 + wn + j * 32 + col)] = (int)v;
            }
}

extern "C" void kernel_launch(void* const* d_in, const int* in_sizes, int n_in,
                              void* d_out, int out_size, void* d_ws, size_t ws_size,
                              hipStream_t stream) {
    const int* x = (const int*)d_in[0];
    const int* w = (const int*)d_in[1];
    const float* pa = (const float*)d_in[2];
    const float* pb = (const float*)d_in[3];
    int* out = (int*)d_out;

    int8_t* a8 = (int8_t*)d_ws;                       // 32 MiB
    int8_t* bt8 = a8 + (size_t)M_DIM * K_DIM;         // 16 MiB

    const int nwords_a = M_DIM * K_DIM / 16;
    pack_a_perm<<<nwords_a / 256, 256, 0, stream>>>(x, (uint4v*)a8);
    transpose_b_perm<<<dim3(N_DIM / 64, K_DIM / 64), 256, 0, stream>>>(w, bt8);
    gemm_kernel<<<dim3(N_DIM / 128, M_DIM / 256), 256, 0, stream>>>(a8, bt8, pa, pb, out);
}

// Round 6
// 407.055 us; speedup vs baseline: 1.1358x; 1.1358x over previous
//
#include <hip/hip_runtime.h>
#include <stdint.h>

typedef __attribute__((ext_vector_type(4))) int int4v;
typedef __attribute__((ext_vector_type(16))) int int16v;
typedef __attribute__((ext_vector_type(4))) uint32_t uint4v;

#define M_DIM 8192
#define N_DIM 4096
#define K_DIM 4096

// K-permuted layout: within each 64-byte K chunk, stored byte p holds
// original k = (p>>2) + 16*(p&3). Applied identically to A and B => MFMA
// dot products unchanged (K-permutation invariance). GEMM XOR-swizzles
// 16-B chunks within each 128-B LDS row (slot = chunk ^ (row&7)), applied
// at the global source address during staging, inverted at fragment-read.

// ---------------- pack x: int32 -> int8, K-permuted ----------------
__global__ void pack_a_perm(const int* __restrict__ x, uint4v* __restrict__ a8) {
    const int g = blockIdx.x * blockDim.x + threadIdx.x;
    const int w0 = (g & 3) * 4;
    const int chunk = g >> 2;
    const int* base = x + (size_t)chunk * 64;
    int4v L[4];
#pragma unroll
    for (int j = 0; j < 4; ++j) L[j] = *(const int4v*)(base + j * 16 + w0);
    uint4v outv;
#pragma unroll
    for (int wi = 0; wi < 4; ++wi) {
        outv[wi] = (uint32_t)(L[0][wi] & 0xff) | ((uint32_t)(L[1][wi] & 0xff) << 8) |
                   ((uint32_t)(L[2][wi] & 0xff) << 16) | ((uint32_t)(L[3][wi] & 0xff) << 24);
    }
    a8[g] = outv;
}

// ------- transpose+pack weight: [K][N] int32 -> Bt[N][K-permuted] int8 -------
__global__ void transpose_b_perm(const int* __restrict__ w, int8_t* __restrict__ bt) {
    const int t = threadIdx.x;
    const int kt = blockIdx.y * 64;
    const int n0 = blockIdx.x * 64;
    const int c4 = t & 3;
    const int n = t >> 2;
    const int w0 = c4 * 4;
    const int* col = w + (size_t)kt * N_DIM + n0 + n;
    uint4v outv;
#pragma unroll
    for (int wi = 0; wi < 4; ++wi) {
        uint32_t p = 0;
#pragma unroll
        for (int j = 0; j < 4; ++j) {
            uint32_t b = (uint32_t)(col[(size_t)(w0 + wi + 16 * j) * N_DIM] & 0xff);
            p |= b << (8 * j);
        }
        outv[wi] = p;
    }
    *(uint4v*)&bt[(size_t)(n0 + n) * K_DIM + kt + w0 * 4] = outv;
}

// ---- GEMM: block 128x128, wave 64x64 (2x2 of 32x32x32), BK=128, reg-diet ----
__device__ inline void async16(const void* g, void* l) {
    __builtin_amdgcn_global_load_lds(
        (const __attribute__((address_space(1))) uint32_t*)g,
        (__attribute__((address_space(3))) uint32_t*)l, 16, 0, 0);
}

__global__ void __launch_bounds__(256, 4)
gemm_kernel(const int8_t* __restrict__ A, const int8_t* __restrict__ Bt,
            const float* __restrict__ pa, const float* __restrict__ pb,
            int* __restrict__ out) {
    __shared__ int8_t smem[32768];
    int8_t* As = smem;            // [128 rows][128 B], chunk-swizzled
    int8_t* Bs = smem + 16384;

    const int t = threadIdx.x;
    const int lane = t & 63;
    const int wave = t >> 6;
    const int m0 = blockIdx.y * 128;
    const int n0 = blockIdx.x * 128;
    const int wm = (wave >> 1) * 64;
    const int wn = (wave & 1) * 64;

    int16v acc[2][2];
#pragma unroll
    for (int i = 0; i < 2; ++i)
#pragma unroll
        for (int j = 0; j < 2; ++j)
#pragma unroll
            for (int r = 0; r < 16; ++r) acc[i][j][r] = 0;

    // staging: row&7 == srow for every step (wave*8 and s*32 are 0 mod 8),
    // so the swizzled chunk offset is step-invariant. A and B share one
    // 32-bit per-lane offset; bases stay in SGPRs.
    const int srow = lane >> 3;
    const int sslot = lane & 7;
    const uint32_t oStage = (uint32_t)(wave * 8 + srow) * K_DIM + ((sslot ^ srow) * 16);
    const uint32_t ldsStage = (uint32_t)(wave * 8) * 128;
    const int8_t* Ab = A + (size_t)m0 * K_DIM;
    const int8_t* Bb = Bt + (size_t)n0 * K_DIM;

    // fragment reads: loop-invariant 32-bit bases
    const int l31 = lane & 31;
    const int fg = lane >> 5;          // k-half selector
    const int c7 = l31 & 7;
    const uint32_t aoff = (uint32_t)(wm + l31) * 128;
    const uint32_t boff = (uint32_t)(wn + l31) * 128;

    for (int kt = 0; kt < K_DIM; kt += 128) {
        __syncthreads();
#pragma unroll
        for (int s = 0; s < 4; ++s) {
            async16(Ab + oStage + kt + s * (32 * K_DIM), As + ldsStage + s * 4096);
            async16(Bb + oStage + kt + s * (32 * K_DIM), Bs + ldsStage + s * 4096);
        }
        __syncthreads();

#pragma unroll
        for (int ks = 0; ks < 4; ++ks) {
            const uint32_t cs = (uint32_t)(((ks * 2 + fg) ^ c7) * 16);
            int4v af[2], bf[2];
#pragma unroll
            for (int i = 0; i < 2; ++i) {
                af[i] = *(const int4v*)&As[aoff + i * 4096 + cs];
                bf[i] = *(const int4v*)&Bs[boff + i * 4096 + cs];
            }
#pragma unroll
            for (int i = 0; i < 2; ++i)
#pragma unroll
                for (int j = 0; j < 2; ++j)
                    acc[i][j] = __builtin_amdgcn_mfma_i32_32x32x32_i8(af[i], bf[j],
                                                                       acc[i][j], 0, 0, 0);
        }
    }

    const float scale = pa[0] * pb[0];
    const int col = lane & 31;
    const int rbase = (lane >> 5) * 4;
#pragma unroll
    for (int i = 0; i < 2; ++i)
#pragma unroll
        for (int j = 0; j < 2; ++j)
#pragma unroll
            for (int r = 0; r < 16; ++r) {
                const int rowf = rbase + (r & 3) + 8 * (r >> 2);
                float v = (float)acc[i][j][r] * scale;
                v = rintf(v);
                v = fminf(127.f, fmaxf(-128.f, v));
                out[(size_t)(m0 + wm + i * 32 + rowf) * N_DIM +
                    (n0 + wn + j * 32 + col)] = (int)v;
            }
}

extern "C" void kernel_launch(void* const* d_in, const int* in_sizes, int n_in,
                              void* d_out, int out_size, void* d_ws, size_t ws_size,
                              hipStream_t stream) {
    const int* x = (const int*)d_in[0];
    const int* w = (const int*)d_in[1];
    const float* pa = (const float*)d_in[2];
    const float* pb = (const float*)d_in[3];
    int* out = (int*)d_out;

    int8_t* a8 = (int8_t*)d_ws;                       // 32 MiB
    int8_t* bt8 = a8 + (size_t)M_DIM * K_DIM;         // 16 MiB

    const int nwords_a = M_DIM * K_DIM / 16;
    pack_a_perm<<<nwords_a / 256, 256, 0, stream>>>(x, (uint4v*)a8);
    transpose_b_perm<<<dim3(N_DIM / 64, K_DIM / 64), 256, 0, stream>>>(w, bt8);
    gemm_kernel<<<dim3(N_DIM / 128, M_DIM / 128), 256, 0, stream>>>(a8, bt8, pa, pb, out);
}